// Round 1
// baseline (406.967 us; speedup 1.0000x reference)
//
#include <hip/hip_runtime.h>
#include <math.h>

// Problem constants (N, Cin, Cout, S, H, W) = (4, 256, 256, 512, 64, 64)
#define NB 4
#define CC 256
#define SS 512
#define PP 4096   // 64*64 working resolution (2x2 output blocks are constant)
#define NL 6
#define PX 32     // pixel tile per block
#define BK 32     // K chunk

// ws layout (floats):
//   wmodAll: [NL][NB][CC][CC]   = 1,572,864
//   stateA : [NB][CC][PP]       = 4,194,304   (x1 / y1 plane, 64x64 res)
//   stateB : [NB][CC][PP]       = 4,194,304   (x2 / y2 plane)
#define WMOD_SZ (NL*NB*CC*CC)
#define ST_SZ   (NB*CC*PP)

__device__ __forceinline__ float gelu_exact(float h) {
    return 0.5f * h * (1.0f + erff(h * 0.70710678118654752f));
}

// ---------------------------------------------------------------------------
// Precompute all layers' normalized modulation matrices.
// wmod[l][b][o][j] = mod_w[l][o][j]*(s+1) / sqrt(sum_j (mod_w[l][o][j]*(s+1))^2 + 1e-8)
// s = affine_w[l][o] . y[b] + affine_b[l][o]
// One 64-thread block per (l,b,o) row.
__global__ __launch_bounds__(64) void wmod_kernel(
    const float* __restrict__ y, const float* __restrict__ aw,
    const float* __restrict__ ab, const float* __restrict__ mw,
    float* __restrict__ wmodAll)
{
    int r = blockIdx.x;            // 0 .. NL*NB*CC-1
    int l = r >> 10;               // /(NB*CC)
    int b = (r >> 8) & 3;
    int o = r & 255;
    int lane = threadIdx.x;

    const float* awr = aw + (size_t)(l*CC + o)*SS;
    const float* yb  = y + (size_t)b*SS;
    float s = 0.f;
#pragma unroll
    for (int j = 0; j < 8; ++j) { int idx = lane + 64*j; s += awr[idx]*yb[idx]; }
#pragma unroll
    for (int off = 32; off; off >>= 1) s += __shfl_xor(s, off);
    float t = s + ab[l*CC + o] + 1.0f;

    const float* mwr = mw + (size_t)(l*CC + o)*CC;
    float w[4]; float ss = 0.f;
#pragma unroll
    for (int u = 0; u < 4; ++u) { int j = lane + 64*u; w[u] = mwr[j]*t; ss += w[u]*w[u]; }
#pragma unroll
    for (int off = 32; off; off >>= 1) ss += __shfl_xor(ss, off);
    float d = 1.0f / sqrtf(ss + 1e-8f);

    float* out = wmodAll + ((size_t)((l*NB + b)*CC + o))*CC;
#pragma unroll
    for (int u = 0; u < 4; ++u) out[lane + 64*u] = w[u]*d;
}

// ---------------------------------------------------------------------------
// Shared GEMM tile geometry: block = 256 threads, tile M=256 (all out chans),
// N=PX pixels, K=CC. Thread (tm = tid&31, tn = tid>>5) owns channels
// m(m8) = 2*tm + 64*(m8>>1) + (m8&1), m8 in [0,8), and pixels tn*4..tn*4+3.
// LDS: Wt[k][m] (pad 260 -> bank (4k+m)%32, conflict-free/2-way),
//      Xt[k][n] (pad 68).

// Conv: state init. acc = ch_conv_w @ x + b; channel o -> stateA rows 2o,2o+1
// (o<128) else stateB rows 2(o-128),2(o-128)+1.  (jnp.repeat axis=1 semantics)
__global__ __launch_bounds__(256) void conv_kernel(
    const float* __restrict__ x, const float* __restrict__ cw,
    const float* __restrict__ cb, float* __restrict__ sA, float* __restrict__ sB)
{
    __shared__ __align__(16) float Wt[BK][260];
    __shared__ __align__(16) float Xt[BK][68];

    int blk = blockIdx.x;
    int b  = blk / (PP/PX);
    int p0 = (blk % (PP/PX)) * PX;
    int tid = threadIdx.x;
    int tm = tid & 31, tn = tid >> 5;

    float acc[8][4];
#pragma unroll
    for (int i = 0; i < 8; ++i)
#pragma unroll
        for (int c = 0; c < 4; ++c) acc[i][c] = 0.f;

    for (int kc = 0; kc < CC/BK; ++kc) {
        int k0 = kc*BK;
        __syncthreads();
        { // stage X chunk: 32 rows x 32 px, 1 float4/thread
            int row = tid >> 3, c4 = tid & 7;
            float4 v = *(const float4*)&x[((size_t)(b*CC + k0 + row))*PP + p0 + c4*4];
            *(float4*)&Xt[row][c4*4] = v;
        }
        // stage W chunk transposed: 256 m x 32 k
#pragma unroll
        for (int j = 0; j < 8; ++j) {
            int m  = (tid >> 3) + 32*j;
            int kf = tid & 7;
            float4 v = *(const float4*)&cw[(size_t)m*CC + k0 + kf*4];
            Wt[kf*4+0][m] = v.x; Wt[kf*4+1][m] = v.y;
            Wt[kf*4+2][m] = v.z; Wt[kf*4+3][m] = v.w;
        }
        __syncthreads();
#pragma unroll 8
        for (int k = 0; k < BK; ++k) {
            float4 xf = *(const float4*)&Xt[k][tn*4];
            float2 w0 = *(const float2*)&Wt[k][2*tm];
            float2 w1 = *(const float2*)&Wt[k][2*tm+64];
            float2 w2 = *(const float2*)&Wt[k][2*tm+128];
            float2 w3 = *(const float2*)&Wt[k][2*tm+192];
            float xv[4] = {xf.x, xf.y, xf.z, xf.w};
            float wv[8] = {w0.x,w0.y,w1.x,w1.y,w2.x,w2.y,w3.x,w3.y};
#pragma unroll
            for (int m8 = 0; m8 < 8; ++m8)
#pragma unroll
                for (int c = 0; c < 4; ++c)
                    acc[m8][c] = fmaf(wv[m8], xv[c], acc[m8][c]);
        }
    }
    // epilogue: bias + channel-duplicated store
#pragma unroll
    for (int m8 = 0; m8 < 8; ++m8) {
        int m = 2*tm + 64*(m8>>1) + (m8&1);
        float bias = cb[m];
        float4 v = make_float4(acc[m8][0]+bias, acc[m8][1]+bias,
                               acc[m8][2]+bias, acc[m8][3]+bias);
        float* base; int row0;
        if (m < 128) { base = sA; row0 = 2*m; }
        else         { base = sB; row0 = 2*(m-128); }
        *(float4*)&base[((size_t)(b*CC + row0  ))*PP + p0 + tn*4] = v;
        *(float4*)&base[((size_t)(b*CC + row0+1))*PP + p0 + tn*4] = v;
    }
}

// Layer update, in place: y1 = a+b (written to sA during staging),
// h = wmod[b] @ y1, y2 = b + gelu(h) (written to sB in epilogue).
// One block owns (batch, pixel tile, ALL 256 out channels) -> race-free.
__global__ __launch_bounds__(256) void layer_kernel(
    const float* __restrict__ wmodAll, float* __restrict__ sA,
    float* __restrict__ sB, int l)
{
    __shared__ __align__(16) float Wt[BK][260];
    __shared__ __align__(16) float Xt[BK][68];

    int blk = blockIdx.x;
    int b  = blk / (PP/PX);
    int p0 = (blk % (PP/PX)) * PX;
    int tid = threadIdx.x;
    int tm = tid & 31, tn = tid >> 5;

    const float* Wg = wmodAll + ((size_t)(l*NB + b))*CC*CC;

    float acc[8][4];
#pragma unroll
    for (int i = 0; i < 8; ++i)
#pragma unroll
        for (int c = 0; c < 4; ++c) acc[i][c] = 0.f;

    for (int kc = 0; kc < CC/BK; ++kc) {
        int k0 = kc*BK;
        __syncthreads();
        { // stage y1 = a+b; also write y1 back over stateA
            int row = tid >> 3, c4 = tid & 7;
            size_t gi = ((size_t)(b*CC + k0 + row))*PP + p0 + c4*4;
            float4 va = *(const float4*)&sA[gi];
            float4 vb = *(const float4*)&sB[gi];
            float4 y1 = make_float4(va.x+vb.x, va.y+vb.y, va.z+vb.z, va.w+vb.w);
            *(float4*)&Xt[row][c4*4] = y1;
            *(float4*)&sA[gi] = y1;
        }
#pragma unroll
        for (int j = 0; j < 8; ++j) {
            int m  = (tid >> 3) + 32*j;
            int kf = tid & 7;
            float4 v = *(const float4*)&Wg[(size_t)m*CC + k0 + kf*4];
            Wt[kf*4+0][m] = v.x; Wt[kf*4+1][m] = v.y;
            Wt[kf*4+2][m] = v.z; Wt[kf*4+3][m] = v.w;
        }
        __syncthreads();
#pragma unroll 8
        for (int k = 0; k < BK; ++k) {
            float4 xf = *(const float4*)&Xt[k][tn*4];
            float2 w0 = *(const float2*)&Wt[k][2*tm];
            float2 w1 = *(const float2*)&Wt[k][2*tm+64];
            float2 w2 = *(const float2*)&Wt[k][2*tm+128];
            float2 w3 = *(const float2*)&Wt[k][2*tm+192];
            float xv[4] = {xf.x, xf.y, xf.z, xf.w};
            float wv[8] = {w0.x,w0.y,w1.x,w1.y,w2.x,w2.y,w3.x,w3.y};
#pragma unroll
            for (int m8 = 0; m8 < 8; ++m8)
#pragma unroll
                for (int c = 0; c < 4; ++c)
                    acc[m8][c] = fmaf(wv[m8], xv[c], acc[m8][c]);
        }
    }
    // epilogue: y2 = b + gelu(h)
#pragma unroll
    for (int m8 = 0; m8 < 8; ++m8) {
        int m = 2*tm + 64*(m8>>1) + (m8&1);
        size_t gi = ((size_t)(b*CC + m))*PP + p0 + tn*4;
        float4 bv = *(const float4*)&sB[gi];
        float4 v;
        v.x = bv.x + gelu_exact(acc[m8][0]);
        v.y = bv.y + gelu_exact(acc[m8][1]);
        v.z = bv.z + gelu_exact(acc[m8][2]);
        v.w = bv.w + gelu_exact(acc[m8][3]);
        *(float4*)&sB[gi] = v;
    }
}

// Final: out = 0.5*(y1+y2), upsampled 2x2 to 128x128. float4 stores.
__global__ __launch_bounds__(256) void final_kernel(
    const float* __restrict__ sA, const float* __restrict__ sB,
    float* __restrict__ out)
{
    int idx = blockIdx.x*256 + threadIdx.x;    // float4 id over (4,256,128,32)
    int Wq = idx & 31;
    int H  = (idx >> 5) & 127;
    int bc = idx >> 12;                        // b*256+c
    size_t src = (size_t)bc*PP + (size_t)(H>>1)*64 + Wq*2;
    float2 a2 = *(const float2*)&sA[src];
    float2 b2 = *(const float2*)&sB[src];
    float v0 = 0.5f*(a2.x+b2.x), v1 = 0.5f*(a2.y+b2.y);
    *(float4*)&out[(size_t)idx*4] = make_float4(v0, v0, v1, v1);
}

extern "C" void kernel_launch(void* const* d_in, const int* in_sizes, int n_in,
                              void* d_out, int out_size, void* d_ws, size_t ws_size,
                              hipStream_t stream) {
    const float* x  = (const float*)d_in[0];
    const float* y  = (const float*)d_in[1];
    const float* cw = (const float*)d_in[2];
    const float* cb = (const float*)d_in[3];
    const float* aw = (const float*)d_in[4];
    const float* ab = (const float*)d_in[5];
    const float* mw = (const float*)d_in[6];
    float* out = (float*)d_out;

    float* ws = (float*)d_ws;
    float* wmodAll = ws;                 // 6*4*256*256
    float* sA = ws + WMOD_SZ;            // 4*256*4096
    float* sB = sA + ST_SZ;              // 4*256*4096

    wmod_kernel<<<NL*NB*CC, 64, 0, stream>>>(y, aw, ab, mw, wmodAll);
    conv_kernel<<<NB*(PP/PX), 256, 0, stream>>>(x, cw, cb, sA, sB);
    for (int l = 0; l < NL; ++l)
        layer_kernel<<<NB*(PP/PX), 256, 0, stream>>>(wmodAll, sA, sB, l);
    final_kernel<<<(NB*CC*128*128/4)/256, 256, 0, stream>>>(sA, sB, out);
}

// Round 2
// 211.475 us; speedup vs baseline: 1.9244x; 1.9244x over previous
//
#include <hip/hip_runtime.h>
#include <math.h>

// (N, Cin, Cout, S, H, W) = (4, 256, 256, 512, 64, 64)
#define NB 4
#define CC 256
#define SS 512
#define NL 6

typedef __attribute__((ext_vector_type(8))) short s16x8;
typedef __attribute__((ext_vector_type(4))) float f32x4;
typedef __attribute__((ext_vector_type(4))) unsigned short u16x4;

__device__ __forceinline__ unsigned short f2bf(float f) {
    unsigned u = __builtin_bit_cast(unsigned, f);
    u += 0x7FFFu + ((u >> 16) & 1u);
    return (unsigned short)(u >> 16);
}
__device__ __forceinline__ float bf2f(unsigned short h) {
    unsigned u = ((unsigned)h) << 16;
    return __builtin_bit_cast(float, u);
}
__device__ __forceinline__ float gelu_exact(float h) {
    return 0.5f * h * (1.0f + erff(h * 0.70710678118654752f));
}

// ---------------------------------------------------------------------------
// wmod[l][b][o][:] = mod_w[l][o][:]*(s+1) / ||mod_w[l][o][:]*(s+1)||, row norm
// with s = affine_w[l][o].y[b] + affine_b[l][o].  One 64-thread block per row.
__global__ __launch_bounds__(64) void wmod_kernel(
    const float* __restrict__ y, const float* __restrict__ aw,
    const float* __restrict__ ab, const float* __restrict__ mw,
    float* __restrict__ wmodAll)
{
    int r = blockIdx.x;            // 0 .. NL*NB*CC-1
    int l = r >> 10;
    int b = (r >> 8) & 3;
    int o = r & 255;
    int lane = threadIdx.x;

    const float* awr = aw + (size_t)(l*CC + o)*SS;
    const float* yb  = y + (size_t)b*SS;
    float s = 0.f;
#pragma unroll
    for (int j = 0; j < 8; ++j) { int idx = lane + 64*j; s += awr[idx]*yb[idx]; }
#pragma unroll
    for (int off = 32; off; off >>= 1) s += __shfl_xor(s, off);
    float t = s + ab[l*CC + o] + 1.0f;

    const float* mwr = mw + (size_t)(l*CC + o)*CC;
    float w[4]; float ss = 0.f;
#pragma unroll
    for (int u = 0; u < 4; ++u) { int j = lane + 64*u; w[u] = mwr[j]*t; ss += w[u]*w[u]; }
#pragma unroll
    for (int off = 32; off; off >>= 1) ss += __shfl_xor(ss, off);
    float d = 1.0f / sqrtf(ss + 1e-8f);

    float* outp = wmodAll + ((size_t)((l*NB + b)*CC + o))*CC;
#pragma unroll
    for (int u = 0; u < 4; ++u) outp[lane + 64*u] = w[u]*d;
}

// ---------------------------------------------------------------------------
// Persistent fused kernel: one block = (batch b, one source row of 64 px, all
// 256 channels). conv GEMM -> 6 layer GEMMs -> 2x2-upsampled output.
// State y1/y2 (and MFMA acc) live in registers in MFMA C/D layout:
//   m(ch) = 64*wm + 16*t + 4*q + reg,  n(px) = 32*wn + 16*s + (lane&15)
// GEMMs: D[m=ch_out][n=px] = sum_k W[m][k] * B[k][n], K=256 in 8 chunks of 32.
// Split-bf16: W,B -> hi+lo; acc += Ah*Bh + Ah*Bl + Al*Bh  (Al*Bl ~ 2^-18 drop)
// MFMA 16x16x32_bf16 fragments (HW-verified layouts):
//   A: lane holds A[m=lane&15][k=(lane>>4)*8+j]; B: B[k=(lane>>4)*8+j][n=lane&15]
//   D: col=lane&15, row=(lane>>4)*4+reg
__global__ __launch_bounds__(512, 2) void fused_kernel(
    const float* __restrict__ x, const float* __restrict__ cw,
    const float* __restrict__ cb, const float* __restrict__ wmodAll,
    float* __restrict__ out)
{
    // LDS: Ah[256][40] Al[256][40] Bh[64][40] Bl[64][40] bf16 (pitch 40 keeps
    // 16B-aligned b128 frag reads, near-conflict-free). Conv epilogue overlays
    // a float scratch [128][66].
    __shared__ __align__(16) unsigned char ldsraw[51200];
    unsigned short* Ah = (unsigned short*)ldsraw;
    unsigned short* Al = Ah + 256*40;
    unsigned short* Bh = Al + 256*40;
    unsigned short* Bl = Bh + 64*40;
    float* S = (float*)ldsraw;     // [128][66] overlay (33792 B)

    const int tid  = threadIdx.x;
    const int lane = tid & 63;
    const int wid  = tid >> 6;     // 0..7
    const int wm   = wid >> 1;     // 0..3  -> m base 64*wm
    const int wn   = wid & 1;      // 0..1  -> n base 32*wn
    const int l15  = lane & 15;
    const int q    = lane >> 4;    // 0..3

    // XCD-swizzle: blockIdx%8 ~ XCD; give each XCD one batch -> wmod L2-resident
    const int bswz  = blockIdx.x & 7;
    const int b     = bswz >> 1;                       // 0..3
    const int strip = ((blockIdx.x >> 3) << 1) | (bswz & 1);  // 0..63 source row
    const int n0    = strip * 64;

    float y1[4][2][4], y2[4][2][4];
    f32x4 acc[4][2];

    // ---------------- conv GEMM:  acc = cw @ x[b]  ----------------
#pragma unroll
    for (int t = 0; t < 4; ++t)
#pragma unroll
        for (int s = 0; s < 2; ++s) acc[t][s] = 0;

    for (int kc = 0; kc < 8; ++kc) {
        __syncthreads();
        {   // stage A chunk (cw rows 0..255, k window) -> split bf16
            int r = tid >> 3, c = tid & 7;
#pragma unroll
            for (int p = 0; p < 4; ++p) {
                int m = r + 64*p;
                float4 v = *(const float4*)&cw[(size_t)m*256 + kc*32 + c*4];
                u16x4 h, l;
                h.x = f2bf(v.x); l.x = f2bf(v.x - bf2f(h.x));
                h.y = f2bf(v.y); l.y = f2bf(v.y - bf2f(h.y));
                h.z = f2bf(v.z); l.z = f2bf(v.z - bf2f(h.z));
                h.w = f2bf(v.w); l.w = f2bf(v.w - bf2f(h.w));
                *(u16x4*)&Ah[m*40 + c*4] = h;
                *(u16x4*)&Al[m*40 + c*4] = l;
            }
        }
        {   // stage B chunk from x (transpose [k][n] -> Bbuf[n][k])
            int r = tid >> 4, c = tid & 15;
            float4 v = *(const float4*)&x[((size_t)(b*CC + kc*32 + r))*4096 + n0 + c*4];
            float vv[4] = {v.x, v.y, v.z, v.w};
#pragma unroll
            for (int j = 0; j < 4; ++j) {
                unsigned short h = f2bf(vv[j]);
                Bh[(c*4 + j)*40 + r] = h;
                Bl[(c*4 + j)*40 + r] = f2bf(vv[j] - bf2f(h));
            }
        }
        __syncthreads();
        s16x8 bh[2], bl[2];
#pragma unroll
        for (int s = 0; s < 2; ++s) {
            bh[s] = *(const s16x8*)&Bh[(wn*32 + s*16 + l15)*40 + q*8];
            bl[s] = *(const s16x8*)&Bl[(wn*32 + s*16 + l15)*40 + q*8];
        }
#pragma unroll
        for (int t = 0; t < 4; ++t) {
            s16x8 ah = *(const s16x8*)&Ah[(wm*64 + t*16 + l15)*40 + q*8];
            s16x8 al = *(const s16x8*)&Al[(wm*64 + t*16 + l15)*40 + q*8];
#pragma unroll
            for (int s = 0; s < 2; ++s) {
                acc[t][s] = __builtin_amdgcn_mfma_f32_16x16x32_bf16(ah, bh[s], acc[t][s], 0, 0, 0);
                acc[t][s] = __builtin_amdgcn_mfma_f32_16x16x32_bf16(ah, bl[s], acc[t][s], 0, 0, 0);
                acc[t][s] = __builtin_amdgcn_mfma_f32_16x16x32_bf16(al, bh[s], acc[t][s], 0, 0, 0);
            }
        }
    }

    // conv epilogue: channel-duplication remap via LDS fp32 scratch, 2 passes.
    // state x1[c] = conv[c>>1]+cb, x2[c] = conv[128+(c>>1)]+cb
#pragma unroll
    for (int pass = 0; pass < 2; ++pass) {
        __syncthreads();
        if ((wm >> 1) == pass) {           // conv channels [128*pass, 128*pass+128)
#pragma unroll
            for (int t = 0; t < 4; ++t)
#pragma unroll
            for (int s = 0; s < 2; ++s)
#pragma unroll
            for (int r = 0; r < 4; ++r) {
                int m  = 64*wm + 16*t + 4*q + r;
                int nl = 32*wn + 16*s + l15;
                S[(m - 128*pass)*66 + nl] = acc[t][s][r] + cb[m];
            }
        }
        __syncthreads();
#pragma unroll
        for (int t = 0; t < 4; ++t)
#pragma unroll
        for (int s = 0; s < 2; ++s)
#pragma unroll
        for (int r = 0; r < 4; ++r) {
            int c  = 64*wm + 16*t + 4*q + r;   // state channel
            int nl = 32*wn + 16*s + l15;
            float v = S[(c >> 1)*66 + nl];
            if (pass == 0) { y1[t][s][r] = v; }
            else           { y2[t][s][r] = v; y1[t][s][r] += v; }
        }
    }
    // now y1 = x1+x2, y2 = x2

    // ---------------- 6 layers, fully register/LDS-resident ----------------
    for (int l = 0; l < NL; ++l) {
        const float* W = wmodAll + ((size_t)(l*NB + b)) * (CC*CC);
#pragma unroll
        for (int t = 0; t < 4; ++t)
#pragma unroll
            for (int s = 0; s < 2; ++s) acc[t][s] = 0;

        for (int kc = 0; kc < 8; ++kc) {
            __syncthreads();
            {   // stage A chunk from wmod
                int r = tid >> 3, c = tid & 7;
#pragma unroll
                for (int p = 0; p < 4; ++p) {
                    int m = r + 64*p;
                    float4 v = *(const float4*)&W[(size_t)m*256 + kc*32 + c*4];
                    u16x4 h, lo;
                    h.x = f2bf(v.x); lo.x = f2bf(v.x - bf2f(h.x));
                    h.y = f2bf(v.y); lo.y = f2bf(v.y - bf2f(h.y));
                    h.z = f2bf(v.z); lo.z = f2bf(v.z - bf2f(h.z));
                    h.w = f2bf(v.w); lo.w = f2bf(v.w - bf2f(h.w));
                    *(u16x4*)&Ah[m*40 + c*4] = h;
                    *(u16x4*)&Al[m*40 + c*4] = lo;
                }
            }
            // stage B chunk from y1 registers (only waves owning this k window)
            if (wm == (kc >> 1)) {
                int tb = (kc & 1) * 2;
#pragma unroll
                for (int th = 0; th < 2; ++th) {
                    int t = tb + th;
#pragma unroll
                    for (int s = 0; s < 2; ++s)
#pragma unroll
                    for (int r = 0; r < 4; ++r) {
                        int kl = 16*th + 4*q + r;      // k local = m - 32*kc
                        int n  = 32*wn + 16*s + l15;
                        float f = y1[t][s][r];
                        unsigned short h = f2bf(f);
                        Bh[n*40 + kl] = h;
                        Bl[n*40 + kl] = f2bf(f - bf2f(h));
                    }
                }
            }
            __syncthreads();
            s16x8 bh[2], bl[2];
#pragma unroll
            for (int s = 0; s < 2; ++s) {
                bh[s] = *(const s16x8*)&Bh[(wn*32 + s*16 + l15)*40 + q*8];
                bl[s] = *(const s16x8*)&Bl[(wn*32 + s*16 + l15)*40 + q*8];
            }
#pragma unroll
            for (int t = 0; t < 4; ++t) {
                s16x8 ah = *(const s16x8*)&Ah[(wm*64 + t*16 + l15)*40 + q*8];
                s16x8 al = *(const s16x8*)&Al[(wm*64 + t*16 + l15)*40 + q*8];
#pragma unroll
                for (int s = 0; s < 2; ++s) {
                    acc[t][s] = __builtin_amdgcn_mfma_f32_16x16x32_bf16(ah, bh[s], acc[t][s], 0, 0, 0);
                    acc[t][s] = __builtin_amdgcn_mfma_f32_16x16x32_bf16(ah, bl[s], acc[t][s], 0, 0, 0);
                    acc[t][s] = __builtin_amdgcn_mfma_f32_16x16x32_bf16(al, bh[s], acc[t][s], 0, 0, 0);
                }
            }
        }
        // y2 += gelu(h);  y1 += y2 (next layer's y1), skip on last layer
#pragma unroll
        for (int t = 0; t < 4; ++t)
#pragma unroll
        for (int s = 0; s < 2; ++s)
#pragma unroll
        for (int r = 0; r < 4; ++r) {
            y2[t][s][r] += gelu_exact(acc[t][s][r]);
            if (l < NL - 1) y1[t][s][r] += y2[t][s][r];
        }
    }

    // ---------------- epilogue: out = 0.5*(y1+y2), 2x2 upsample ----------------
#pragma unroll
    for (int t = 0; t < 4; ++t)
#pragma unroll
    for (int s = 0; s < 2; ++s)
#pragma unroll
    for (int r = 0; r < 4; ++r) {
        int ch = 64*wm + 16*t + 4*q + r;
        int w  = 32*wn + 16*s + l15;
        float v = 0.5f*(y1[t][s][r] + y2[t][s][r]);
        float2 vv = make_float2(v, v);
        size_t base = (((size_t)(b*CC + ch)*128 + 2*strip))*128 + 2*w;
        *(float2*)&out[base]       = vv;
        *(float2*)&out[base + 128] = vv;
    }
}

extern "C" void kernel_launch(void* const* d_in, const int* in_sizes, int n_in,
                              void* d_out, int out_size, void* d_ws, size_t ws_size,
                              hipStream_t stream) {
    const float* x  = (const float*)d_in[0];
    const float* y  = (const float*)d_in[1];
    const float* cw = (const float*)d_in[2];
    const float* cb = (const float*)d_in[3];
    const float* aw = (const float*)d_in[4];
    const float* ab = (const float*)d_in[5];
    const float* mw = (const float*)d_in[6];
    float* out = (float*)d_out;

    float* wmodAll = (float*)d_ws;   // 6*4*256*256 floats = 6.3 MB

    wmod_kernel<<<NL*NB*CC, 64, 0, stream>>>(y, aw, ab, mw, wmodAll);
    fused_kernel<<<256, 512, 0, stream>>>(x, cw, cb, wmodAll, out);
}

// Round 3
// 158.771 us; speedup vs baseline: 2.5632x; 1.3319x over previous
//
#include <hip/hip_runtime.h>
#include <math.h>

// (N, Cin, Cout, S, H, W) = (4, 256, 256, 512, 64, 64)
#define NB 4
#define CC 256
#define SS 512
#define NL 6
#define PITCH 72                  // halfwords per row of a staged A/B quarter
#define AQ_HW (256*PITCH)         // 18432 halfwords = 36864 B per A-quarter slot
#define NDMA 36                   // 36 x 1KB DMA insts per A quarter

typedef __attribute__((ext_vector_type(8))) short s16x8;
typedef __attribute__((ext_vector_type(4))) float f32x4;

__device__ __forceinline__ unsigned short f2bf(float f) {
    unsigned u = __builtin_bit_cast(unsigned, f);
    u += 0x7FFFu + ((u >> 16) & 1u);
    return (unsigned short)(u >> 16);
}
__device__ __forceinline__ float bf2f(unsigned short h) {
    unsigned u = ((unsigned)h) << 16;
    return __builtin_bit_cast(float, u);
}
// gelu_exact(x)=0.5x(1+erf(x/sqrt2)) ~= x*sigmoid(1.5957691216*(x+0.044715x^3))
// max abs dev ~3e-3 -- far inside the 2% threshold.
__device__ __forceinline__ float gelu_fast(float x) {
    float u = x * (1.0f + 0.044715f * x * x);
    float e = __expf(-1.5957691216f * u);
    return x / (1.0f + e);
}
// async global->LDS, 16B per lane. lds arg = wave-uniform base (HW adds lane*16).
__device__ __forceinline__ void glds16(const void* g, void* l) {
    __builtin_amdgcn_global_load_lds(
        (const __attribute__((address_space(1))) unsigned int*)g,
        (__attribute__((address_space(3))) unsigned int*)(unsigned int)(unsigned long long)l,
        16, 0, 0);
}

// ---------------------------------------------------------------------------
// wmod rows -> bf16 (RNE) directly into padded per-quarter A slots in ws.
// slot(l,b,kq) holds [m=256][PITCH] halfwords, cols 0..63 = k in [64kq,64kq+64).
__global__ __launch_bounds__(256) void wmod_kernel(
    const float* __restrict__ y, const float* __restrict__ aw,
    const float* __restrict__ ab, const float* __restrict__ mw,
    unsigned short* __restrict__ wsBF)
{
    int w = threadIdx.x >> 6, lane = threadIdx.x & 63;
    int r = blockIdx.x*4 + w;      // 0 .. 6143
    int l = r >> 10;
    int b = (r >> 8) & 3;
    int o = r & 255;

    const float* awr = aw + (size_t)(l*CC + o)*SS;
    const float* yb  = y + (size_t)b*SS;
    float s = 0.f;
#pragma unroll
    for (int j = 0; j < 8; ++j) { int idx = lane + 64*j; s += awr[idx]*yb[idx]; }
#pragma unroll
    for (int off = 32; off; off >>= 1) s += __shfl_xor(s, off);
    float t = s + ab[l*CC + o] + 1.0f;

    const float* mwr = mw + (size_t)(l*CC + o)*CC;
    float wv[4]; float ss = 0.f;
#pragma unroll
    for (int u = 0; u < 4; ++u) { int j = lane + 64*u; wv[u] = mwr[j]*t; ss += wv[u]*wv[u]; }
#pragma unroll
    for (int off = 32; off; off >>= 1) ss += __shfl_xor(ss, off);
    float d = 1.0f / sqrtf(ss + 1e-8f);

#pragma unroll
    for (int u = 0; u < 4; ++u)    // k = lane + 64u -> quarter u, col lane
        wsBF[(size_t)(4 + (l*NB + b)*4 + u)*AQ_HW + o*PITCH + lane] = f2bf(wv[u]*d);
}

// cw -> bf16 padded quarter slots 0..3 of ws.
__global__ __launch_bounds__(256) void cwsplit_kernel(
    const float* __restrict__ cw, unsigned short* __restrict__ wsBF)
{
    int w = threadIdx.x >> 6, lane = threadIdx.x & 63;
    int m = blockIdx.x*4 + w;      // 0..255
#pragma unroll
    for (int u = 0; u < 4; ++u)
        wsBF[(size_t)u*AQ_HW + m*PITCH + lane] = f2bf(cw[(size_t)m*CC + 64*u + lane]);
}

// ---------------------------------------------------------------------------
// Fused: one block = (batch, 64-px source row, all 256 channels).
// A (weights): bf16-rounded, DMA'd from ws (zero VALU staging).
// B (activations): exact hi+lo split -> 2 MFMA per tile (Ah*Bh + Ah*Bl).
// State y1/y2 fp32 in registers (MFMA C/D layout), never quantized.
__global__ __launch_bounds__(512, 2) void fused_kernel(
    const float* __restrict__ x, const float* __restrict__ cb,
    const unsigned short* __restrict__ wsBF, float* __restrict__ out)
{
    // LDS: Bh[64][72] (9216B) | Bl[64][72] (9216B) | Ah[256][72] (36864B) = 54KB
    // Conv-epilogue overlays float S[128][66] (33792B) at offset 0.
    __shared__ __align__(16) unsigned char lds[55296];
    unsigned short* Bh = (unsigned short*)lds;
    unsigned short* Bl = Bh + 64*PITCH;
    unsigned short* Ah = (unsigned short*)(lds + 18432);
    float* S = (float*)lds;

    const int tid  = threadIdx.x;
    const int lane = tid & 63;
    const int wid  = tid >> 6;     // 0..7
    const int wm   = wid >> 1;     // 0..3  m base 64*wm
    const int wn   = wid & 1;      // 0..1  n base 32*wn
    const int l15  = lane & 15;
    const int q    = lane >> 4;    // 0..3

    // XCD swizzle: each XCD pair-slot -> one batch (weights L2-resident)
    const int bswz  = blockIdx.x & 7;
    const int b     = bswz >> 1;
    const int strip = ((blockIdx.x >> 3) << 1) | (bswz & 1);   // 0..63
    const int n0    = strip * 64;

    float y1[4][2][4], y2[4][2][4];
    f32x4 acc[4][2];

    // ---------------- conv GEMM ----------------
#pragma unroll
    for (int t = 0; t < 4; ++t)
#pragma unroll
        for (int s = 0; s < 2; ++s) acc[t][s] = 0;

    for (int kq = 0; kq < 4; ++kq) {
        __syncthreads();
        {   // stage x window -> split bf16 B[n][k]
#pragma unroll
            for (int c = 0; c < 2; ++c) {
                int v = tid*2 + c;
                int row = v >> 4, col4 = (v & 15) * 4;
                float4 xv = *(const float4*)&x[((size_t)(b*CC + kq*64 + row))*4096 + n0 + col4];
                float f[4] = {xv.x, xv.y, xv.z, xv.w};
#pragma unroll
                for (int j = 0; j < 4; ++j) {
                    unsigned short h = f2bf(f[j]);
                    Bh[(col4+j)*PITCH + row] = h;
                    Bl[(col4+j)*PITCH + row] = f2bf(f[j] - bf2f(h));
                }
            }
        }
        {   // DMA cw quarter
            const char* gA = (const char*)(wsBF + (size_t)kq*AQ_HW);
#pragma unroll
            for (int j = 0; j < 5; ++j) {
                int i = wid + 8*j;
                if (i < NDMA) glds16(gA + i*1024 + lane*16, (char*)Ah + i*1024);
            }
        }
        __syncthreads();
#pragma unroll
        for (int kcl = 0; kcl < 2; ++kcl) {
            s16x8 bh[2], bl[2];
#pragma unroll
            for (int s = 0; s < 2; ++s) {
                bh[s] = *(const s16x8*)&Bh[(32*wn + 16*s + l15)*PITCH + kcl*32 + q*8];
                bl[s] = *(const s16x8*)&Bl[(32*wn + 16*s + l15)*PITCH + kcl*32 + q*8];
            }
#pragma unroll
            for (int t = 0; t < 4; ++t) {
                s16x8 ah = *(const s16x8*)&Ah[(64*wm + 16*t + l15)*PITCH + kcl*32 + q*8];
#pragma unroll
                for (int s = 0; s < 2; ++s) {
                    acc[t][s] = __builtin_amdgcn_mfma_f32_16x16x32_bf16(ah, bh[s], acc[t][s], 0, 0, 0);
                    acc[t][s] = __builtin_amdgcn_mfma_f32_16x16x32_bf16(ah, bl[s], acc[t][s], 0, 0, 0);
                }
            }
        }
    }

    // conv epilogue: bias + channel-duplication remap via fp32 LDS scratch.
    // x1[c] = conv[c>>1]+cb, x2[c] = conv[128+(c>>1)]+cb
#pragma unroll
    for (int pass = 0; pass < 2; ++pass) {
        __syncthreads();
        if ((wm >> 1) == pass) {
#pragma unroll
            for (int t = 0; t < 4; ++t)
#pragma unroll
            for (int s = 0; s < 2; ++s)
#pragma unroll
            for (int r = 0; r < 4; ++r) {
                int m  = 64*wm + 16*t + 4*q + r;
                int nl = 32*wn + 16*s + l15;
                S[(m - 128*pass)*66 + nl] = acc[t][s][r] + cb[m];
            }
        }
        __syncthreads();
#pragma unroll
        for (int t = 0; t < 4; ++t)
#pragma unroll
        for (int s = 0; s < 2; ++s)
#pragma unroll
        for (int r = 0; r < 4; ++r) {
            int c  = 64*wm + 16*t + 4*q + r;
            int nl = 32*wn + 16*s + l15;
            float v = S[(c >> 1)*66 + nl];
            if (pass == 0) { y1[t][s][r] = v; }
            else           { y2[t][s][r] = v; y1[t][s][r] += v; }
        }
    }
    // y1 = x1+x2, y2 = x2

    // ---------------- 6 layers ----------------
    for (int l = 0; l < NL; ++l) {
        const unsigned short* Wl = wsBF + (size_t)(4 + (l*NB + b)*4)*AQ_HW;
#pragma unroll
        for (int t = 0; t < 4; ++t)
#pragma unroll
            for (int s = 0; s < 2; ++s) acc[t][s] = 0;

        for (int kq = 0; kq < 4; ++kq) {
            __syncthreads();
            // stage B quarter from y1 regs (owner wave-group: wm == kq)
            if (wm == kq) {
#pragma unroll
                for (int t = 0; t < 4; ++t)
#pragma unroll
                for (int s = 0; s < 2; ++s)
#pragma unroll
                for (int pr = 0; pr < 2; ++pr) {
                    int kloc = 16*t + 4*q + 2*pr;       // even
                    int n = 32*wn + 16*s + l15;
                    float f0 = y1[t][s][2*pr], f1 = y1[t][s][2*pr+1];
                    unsigned short h0 = f2bf(f0), h1 = f2bf(f1);
                    unsigned short g0 = f2bf(f0 - bf2f(h0)), g1 = f2bf(f1 - bf2f(h1));
                    *(unsigned*)&Bh[n*PITCH + kloc] = (unsigned)h0 | ((unsigned)h1 << 16);
                    *(unsigned*)&Bl[n*PITCH + kloc] = (unsigned)g0 | ((unsigned)g1 << 16);
                }
            }
            {   // DMA wmod quarter
                const char* gA = (const char*)(Wl + (size_t)kq*AQ_HW);
#pragma unroll
                for (int j = 0; j < 5; ++j) {
                    int i = wid + 8*j;
                    if (i < NDMA) glds16(gA + i*1024 + lane*16, (char*)Ah + i*1024);
                }
            }
            __syncthreads();
#pragma unroll
            for (int kcl = 0; kcl < 2; ++kcl) {
                s16x8 bh[2], bl[2];
#pragma unroll
                for (int s = 0; s < 2; ++s) {
                    bh[s] = *(const s16x8*)&Bh[(32*wn + 16*s + l15)*PITCH + kcl*32 + q*8];
                    bl[s] = *(const s16x8*)&Bl[(32*wn + 16*s + l15)*PITCH + kcl*32 + q*8];
                }
#pragma unroll
                for (int t = 0; t < 4; ++t) {
                    s16x8 ah = *(const s16x8*)&Ah[(64*wm + 16*t + l15)*PITCH + kcl*32 + q*8];
#pragma unroll
                    for (int s = 0; s < 2; ++s) {
                        acc[t][s] = __builtin_amdgcn_mfma_f32_16x16x32_bf16(ah, bh[s], acc[t][s], 0, 0, 0);
                        acc[t][s] = __builtin_amdgcn_mfma_f32_16x16x32_bf16(ah, bl[s], acc[t][s], 0, 0, 0);
                    }
                }
            }
        }
        // y2 += gelu(h); y1 += y2 (next layer), skip on last
#pragma unroll
        for (int t = 0; t < 4; ++t)
#pragma unroll
        for (int s = 0; s < 2; ++s)
#pragma unroll
        for (int r = 0; r < 4; ++r) {
            y2[t][s][r] += gelu_fast(acc[t][s][r]);
            if (l < NL - 1) y1[t][s][r] += y2[t][s][r];
        }
    }

    // ---------------- out = 0.5*(y1+y2), 2x2 upsample ----------------
#pragma unroll
    for (int t = 0; t < 4; ++t)
#pragma unroll
    for (int s = 0; s < 2; ++s)
#pragma unroll
    for (int r = 0; r < 4; ++r) {
        int ch = 64*wm + 16*t + 4*q + r;
        int w  = 32*wn + 16*s + l15;
        float v = 0.5f*(y1[t][s][r] + y2[t][s][r]);
        float2 vv = make_float2(v, v);
        size_t base = (((size_t)(b*CC + ch)*128 + 2*strip))*128 + 2*w;
        *(float2*)&out[base]       = vv;
        *(float2*)&out[base + 128] = vv;
    }
}

extern "C" void kernel_launch(void* const* d_in, const int* in_sizes, int n_in,
                              void* d_out, int out_size, void* d_ws, size_t ws_size,
                              hipStream_t stream) {
    const float* x  = (const float*)d_in[0];
    const float* y  = (const float*)d_in[1];
    const float* cw = (const float*)d_in[2];
    const float* cb = (const float*)d_in[3];
    const float* aw = (const float*)d_in[4];
    const float* ab = (const float*)d_in[5];
    const float* mw = (const float*)d_in[6];
    float* out = (float*)d_out;

    unsigned short* wsBF = (unsigned short*)d_ws;   // 100 slots * 36864 B = 3.7 MB

    wmod_kernel<<<NL*NB*CC/4, 256, 0, stream>>>(y, aw, ab, mw, wsBF);
    cwsplit_kernel<<<64, 256, 0, stream>>>(cw, wsBF);
    fused_kernel<<<256, 512, 0, stream>>>(x, cb, wsBF, out);
}

// Round 5
// 154.537 us; speedup vs baseline: 2.6335x; 1.0274x over previous
//
#include <hip/hip_runtime.h>
#include <math.h>

// (N, Cin, Cout, S, H, W) = (4, 256, 256, 512, 64, 64)
#define NB 4
#define CC 256
#define SS 512
#define NL 6
#define PITCH 72                  // halfwords per row of a staged A/B tile
#define AQ_HW (256*PITCH)         // 18432 halfwords = 36864 B per A-quarter slot
#define NDMA 36                   // 36 x 1KB DMA insts per A quarter

typedef __attribute__((ext_vector_type(8))) short s16x8;
typedef __attribute__((ext_vector_type(4))) float f32x4;
typedef __attribute__((ext_vector_type(4))) unsigned short u16x4;

__device__ __forceinline__ unsigned short f2bf(float f) {
    unsigned u = __builtin_bit_cast(unsigned, f);
    u += 0x7FFFu + ((u >> 16) & 1u);
    return (unsigned short)(u >> 16);
}
__device__ __forceinline__ float bf2f(unsigned short h) {
    unsigned u = ((unsigned)h) << 16;
    return __builtin_bit_cast(float, u);
}
// gelu_exact(x) ~= x*sigmoid(1.5957691216*(x+0.044715x^3)), |err|<3e-3
__device__ __forceinline__ float gelu_fast(float x) {
    float u = x * (1.0f + 0.044715f * x * x);
    float e = __expf(-1.5957691216f * u);
    return x / (1.0f + e);
}
// async global->LDS, 16B per lane. lds arg = wave-uniform base (HW adds lane*16).
__device__ __forceinline__ void glds16(const void* g, void* l) {
    __builtin_amdgcn_global_load_lds(
        (const __attribute__((address_space(1))) unsigned int*)g,
        (__attribute__((address_space(3))) unsigned int*)(unsigned int)(unsigned long long)l,
        16, 0, 0);
}

// ---------------------------------------------------------------------------
// wmod rows -> bf16 (RNE) into padded per-quarter A slots in ws.
// slot(l,b,kq) holds [m=256][PITCH] halfwords, cols 0..63 = k in [64kq,64kq+64).
__global__ __launch_bounds__(256) void wmod_kernel(
    const float* __restrict__ y, const float* __restrict__ aw,
    const float* __restrict__ ab, const float* __restrict__ mw,
    unsigned short* __restrict__ wsBF)
{
    int w = threadIdx.x >> 6, lane = threadIdx.x & 63;
    int r = blockIdx.x*4 + w;      // 0 .. 6143
    int l = r >> 10;
    int b = (r >> 8) & 3;
    int o = r & 255;

    const float* awr = aw + (size_t)(l*CC + o)*SS;
    const float* yb  = y + (size_t)b*SS;
    float s = 0.f;
#pragma unroll
    for (int j = 0; j < 8; ++j) { int idx = lane + 64*j; s += awr[idx]*yb[idx]; }
#pragma unroll
    for (int off = 32; off; off >>= 1) s += __shfl_xor(s, off);
    float t = s + ab[l*CC + o] + 1.0f;

    const float* mwr = mw + (size_t)(l*CC + o)*CC;
    float wv[4]; float ss = 0.f;
#pragma unroll
    for (int u = 0; u < 4; ++u) { int j = lane + 64*u; wv[u] = mwr[j]*t; ss += wv[u]*wv[u]; }
#pragma unroll
    for (int off = 32; off; off >>= 1) ss += __shfl_xor(ss, off);
    float d = 1.0f / sqrtf(ss + 1e-8f);

#pragma unroll
    for (int u = 0; u < 4; ++u)    // k = lane + 64u -> quarter u, col lane
        wsBF[(size_t)(4 + (l*NB + b)*4 + u)*AQ_HW + o*PITCH + lane] = f2bf(wv[u]*d);
}

// cw -> bf16 padded quarter slots 0..3 of ws.
__global__ __launch_bounds__(256) void cwsplit_kernel(
    const float* __restrict__ cw, unsigned short* __restrict__ wsBF)
{
    int w = threadIdx.x >> 6, lane = threadIdx.x & 63;
    int m = blockIdx.x*4 + w;      // 0..255
#pragma unroll
    for (int u = 0; u < 4; ++u)
        wsBF[(size_t)u*AQ_HW + m*PITCH + lane] = f2bf(cw[(size_t)m*CC + 64*u + lane]);
}

// ---------------------------------------------------------------------------
// Fused: one block = (batch, 32-px half-strip, all 256 channels).
// Grid 512 -> 2 blocks/CU: one block's MFMA hides the other's barriers/DMA.
// A (weights): bf16-rounded, DMA'd from ws. B (activations): exact hi+lo
// split -> 2 MFMA/tile. State y1/y2 fp32 in regs (MFMA C/D layout).
__global__ __launch_bounds__(512, 4) void fused_kernel(
    const float* __restrict__ x, const float* __restrict__ cb,
    const unsigned short* __restrict__ wsBF, float* __restrict__ out)
{
    // LDS (55296 B): Bh[32][72]hw @0 (4608) | Bl @4608 (4608) |
    // xS f32[64][36] @9216 (9216, ends 18432) | Ah[256][72]hw @18432 (36864).
    // Conv epilogue overlays S2 f32[128][33] @0 (16896 B, covers Bh/Bl/xS only;
    // Ah untouched). NOTE r4 bug: Ah was at 17664, overlapping xS rows>=59 ->
    // DMA/store race fed NaN bf16 patterns into MFMA. Ah MUST be >= 18432.
    __shared__ __align__(16) unsigned char lds[55296];
    unsigned short* Bh = (unsigned short*)lds;
    unsigned short* Bl = (unsigned short*)(lds + 4608);
    float*          xS = (float*)(lds + 9216);
    unsigned short* Ah = (unsigned short*)(lds + 18432);
    float*          S2 = (float*)lds;

    const int tid  = threadIdx.x;
    const int lane = tid & 63;
    const int wid  = tid >> 6;     // 0..7
    const int wm   = wid >> 1;     // 0..3  m base 64*wm
    const int wn   = wid & 1;      // 0..1  n base 16*wn
    const int l15  = lane & 15;
    const int q    = lane >> 4;    // 0..3

    // XCD swizzle: blockIdx%8 -> (batch, half) fixed per XCD -> weights L2-resident
    const int bswz  = blockIdx.x & 7;
    const int b     = bswz >> 1;               // 0..3
    const int half  = bswz & 1;                // 0..1
    const int strip = blockIdx.x >> 3;         // 0..63 source row
    const int n0    = strip * 64 + half * 32;  // 32-px window

    float y1[4][4], y2[4][4];
    f32x4 acc[4];

    // ---------------- conv GEMM:  acc = cw @ x[b]  ----------------
#pragma unroll
    for (int t = 0; t < 4; ++t) acc[t] = 0;

    for (int kq = 0; kq < 4; ++kq) {
        __syncthreads();
        {   // coalesced fp32 stage of x window [64k x 32n] (conflict-free)
            int row = tid >> 3, col4 = (tid & 7) * 4;
            float4 xv = *(const float4*)&x[((size_t)(b*CC + kq*64 + row))*4096 + n0 + col4];
            *(float4*)&xS[row*36 + col4] = xv;
        }
        {   // DMA cw quarter
            const char* gA = (const char*)(wsBF + (size_t)kq*AQ_HW);
#pragma unroll
            for (int j = 0; j < 5; ++j) {
                int i = wid + 8*j;
                if (i < NDMA) glds16(gA + i*1024 + lane*16, (char*)Ah + i*1024);
            }
        }
        __syncthreads();
        {   // transposed read (2-way, free) -> split bf16 -> k-contiguous 8B writes
            int n = tid & 31, k0 = (tid >> 5) * 4;
            float f[4];
#pragma unroll
            for (int i = 0; i < 4; ++i) f[i] = xS[(k0+i)*36 + n];
            u16x4 hv, lv;
#pragma unroll
            for (int i = 0; i < 4; ++i) {
                unsigned short h = f2bf(f[i]);
                hv[i] = h; lv[i] = f2bf(f[i] - bf2f(h));
            }
            *(u16x4*)&Bh[n*PITCH + k0] = hv;
            *(u16x4*)&Bl[n*PITCH + k0] = lv;
        }
        __syncthreads();
#pragma unroll
        for (int kcl = 0; kcl < 2; ++kcl) {
            s16x8 bh = *(const s16x8*)&Bh[(16*wn + l15)*PITCH + kcl*32 + q*8];
            s16x8 bl = *(const s16x8*)&Bl[(16*wn + l15)*PITCH + kcl*32 + q*8];
#pragma unroll
            for (int t = 0; t < 4; ++t) {
                s16x8 ah = *(const s16x8*)&Ah[(64*wm + 16*t + l15)*PITCH + kcl*32 + q*8];
                acc[t] = __builtin_amdgcn_mfma_f32_16x16x32_bf16(ah, bh, acc[t], 0, 0, 0);
                acc[t] = __builtin_amdgcn_mfma_f32_16x16x32_bf16(ah, bl, acc[t], 0, 0, 0);
            }
        }
    }

    // conv epilogue: bias + channel-duplication remap via fp32 LDS scratch.
    // x1[c] = conv[c>>1]+cb, x2[c] = conv[128+(c>>1)]+cb
#pragma unroll
    for (int pass = 0; pass < 2; ++pass) {
        __syncthreads();
        if ((wm >> 1) == pass) {
#pragma unroll
            for (int t = 0; t < 4; ++t)
#pragma unroll
            for (int r = 0; r < 4; ++r) {
                int m  = 64*wm + 16*t + 4*q + r;
                int nl = 16*wn + l15;
                S2[(m - 128*pass)*33 + nl] = acc[t][r] + cb[m];
            }
        }
        __syncthreads();
#pragma unroll
        for (int t = 0; t < 4; ++t)
#pragma unroll
        for (int r = 0; r < 4; ++r) {
            int c  = 64*wm + 16*t + 4*q + r;
            int nl = 16*wn + l15;
            float v = S2[(c >> 1)*33 + nl];
            if (pass == 0) { y1[t][r] = v; }
            else           { y2[t][r] = v; y1[t][r] += v; }
        }
    }
    // y1 = x1+x2, y2 = x2

    // ---------------- 6 layers ----------------
    for (int l = 0; l < NL; ++l) {
        const unsigned short* Wl = wsBF + (size_t)(4 + (l*NB + b)*4)*AQ_HW;
#pragma unroll
        for (int t = 0; t < 4; ++t) acc[t] = 0;

        for (int kq = 0; kq < 4; ++kq) {
            __syncthreads();
            // stage B quarter from y1 regs (owner wave-group: wm == kq)
            if (wm == kq) {
#pragma unroll
                for (int t = 0; t < 4; ++t)
#pragma unroll
                for (int pr = 0; pr < 2; ++pr) {
                    int kloc = 16*t + 4*q + 2*pr;       // even
                    int n = 16*wn + l15;
                    float f0 = y1[t][2*pr], f1 = y1[t][2*pr+1];
                    unsigned short h0 = f2bf(f0), h1 = f2bf(f1);
                    unsigned short g0 = f2bf(f0 - bf2f(h0)), g1 = f2bf(f1 - bf2f(h1));
                    *(unsigned*)&Bh[n*PITCH + kloc] = (unsigned)h0 | ((unsigned)h1 << 16);
                    *(unsigned*)&Bl[n*PITCH + kloc] = (unsigned)g0 | ((unsigned)g1 << 16);
                }
            }
            {   // DMA wmod quarter
                const char* gA = (const char*)(Wl + (size_t)kq*AQ_HW);
#pragma unroll
                for (int j = 0; j < 5; ++j) {
                    int i = wid + 8*j;
                    if (i < NDMA) glds16(gA + i*1024 + lane*16, (char*)Ah + i*1024);
                }
            }
            __syncthreads();
#pragma unroll
            for (int kcl = 0; kcl < 2; ++kcl) {
                s16x8 bh = *(const s16x8*)&Bh[(16*wn + l15)*PITCH + kcl*32 + q*8];
                s16x8 bl = *(const s16x8*)&Bl[(16*wn + l15)*PITCH + kcl*32 + q*8];
#pragma unroll
                for (int t = 0; t < 4; ++t) {
                    s16x8 ah = *(const s16x8*)&Ah[(64*wm + 16*t + l15)*PITCH + kcl*32 + q*8];
                    acc[t] = __builtin_amdgcn_mfma_f32_16x16x32_bf16(ah, bh, acc[t], 0, 0, 0);
                    acc[t] = __builtin_amdgcn_mfma_f32_16x16x32_bf16(ah, bl, acc[t], 0, 0, 0);
                }
            }
        }
        // y2 += gelu(h); y1 += y2 (next layer), skip on last
#pragma unroll
        for (int t = 0; t < 4; ++t)
#pragma unroll
        for (int r = 0; r < 4; ++r) {
            y2[t][r] += gelu_fast(acc[t][r]);
            if (l < NL - 1) y1[t][r] += y2[t][r];
        }
    }

    // ---------------- out = 0.5*(y1+y2), 2x2 upsample ----------------
#pragma unroll
    for (int t = 0; t < 4; ++t)
#pragma unroll
    for (int r = 0; r < 4; ++r) {
        int ch = 64*wm + 16*t + 4*q + r;
        int w  = half*32 + 16*wn + l15;      // 0..63 source col
        float v = 0.5f*(y1[t][r] + y2[t][r]);
        float2 vv = make_float2(v, v);
        size_t base = (((size_t)(b*CC + ch)*128 + 2*strip))*128 + 2*w;
        *(float2*)&out[base]       = vv;
        *(float2*)&out[base + 128] = vv;
    }
}

extern "C" void kernel_launch(void* const* d_in, const int* in_sizes, int n_in,
                              void* d_out, int out_size, void* d_ws, size_t ws_size,
                              hipStream_t stream) {
    const float* x  = (const float*)d_in[0];
    const float* y  = (const float*)d_in[1];
    const float* cw = (const float*)d_in[2];
    const float* cb = (const float*)d_in[3];
    const float* aw = (const float*)d_in[4];
    const float* ab = (const float*)d_in[5];
    const float* mw = (const float*)d_in[6];
    float* out = (float*)d_out;

    unsigned short* wsBF = (unsigned short*)d_ws;   // 100 slots * 36864 B = 3.7 MB

    wmod_kernel<<<NL*NB*CC/4, 256, 0, stream>>>(y, aw, ab, mw, wsBF);
    cwsplit_kernel<<<64, 256, 0, stream>>>(cw, wsBF);
    fused_kernel<<<512, 512, 0, stream>>>(x, cb, wsBF, out);
}

// Round 6
// 141.138 us; speedup vs baseline: 2.8835x; 1.0949x over previous
//
#include <hip/hip_runtime.h>
#include <math.h>

// (N, Cin, Cout, S, H, W) = (4, 256, 256, 512, 64, 64)
#define NB 4
#define CC 256
#define SS 512
#define NL 6
#define SLOT_HW 65536   // 128 KB per weight slot, MFMA-A-fragment-packed

typedef __attribute__((ext_vector_type(8))) short s16x8;
typedef __attribute__((ext_vector_type(4))) float f32x4;
typedef __attribute__((ext_vector_type(4))) unsigned short u16x4;
typedef __attribute__((ext_vector_type(8))) unsigned short u16x8;

__device__ __forceinline__ unsigned short f2bf(float f) {
    unsigned u = __builtin_bit_cast(unsigned, f);
    u += 0x7FFFu + ((u >> 16) & 1u);
    return (unsigned short)(u >> 16);
}
__device__ __forceinline__ float bf2f(unsigned short h) {
    unsigned u = ((unsigned)h) << 16;
    return __builtin_bit_cast(float, u);
}
// gelu_exact(x) ~= x*sigmoid(1.5957691216*(x+0.044715x^3)), |err|<3e-3
__device__ __forceinline__ float gelu_fast(float x) {
    float u = x * (1.0f + 0.044715f * x * x);
    float e = __expf(-1.5957691216f * u);
    return x / (1.0f + e);
}

// Fragment-packed weight layout, per 256x256 GEMM slot (128 KB):
// fragment f = (m>>4)*8 + (k>>5); inside: halfword offset
//   ((k>>3)&3)*128 + (m&15)*8 + (k&7)   [= lane'*8 + j, lane' = 16q + m15]
// so a wave's A-fragment read is slot + f*512 + lane*8 (16 B/lane contiguous).

// ---------------------------------------------------------------------------
// wmod rows -> bf16 fragments. wmod = mod_w[l][o]*(s+1), row-normalized.
__global__ __launch_bounds__(256) void wmod_kernel(
    const float* __restrict__ y, const float* __restrict__ aw,
    const float* __restrict__ ab, const float* __restrict__ mw,
    unsigned short* __restrict__ wsBF)
{
    int w = threadIdx.x >> 6, lane = threadIdx.x & 63;
    int r = blockIdx.x*4 + w;      // 0 .. 6143
    int l = r >> 10;
    int b = (r >> 8) & 3;
    int o = r & 255;

    const float* awr = aw + (size_t)(l*CC + o)*SS;
    const float* yb  = y + (size_t)b*SS;
    float s = 0.f;
#pragma unroll
    for (int j = 0; j < 8; ++j) { int idx = lane + 64*j; s += awr[idx]*yb[idx]; }
#pragma unroll
    for (int off = 32; off; off >>= 1) s += __shfl_xor(s, off);
    float t = s + ab[l*CC + o] + 1.0f;

    const float* mwr = mw + (size_t)(l*CC + o)*CC;
    float wv[4]; float ss = 0.f;
#pragma unroll
    for (int u = 0; u < 4; ++u) { int j = lane + 64*u; wv[u] = mwr[j]*t; ss += wv[u]*wv[u]; }
#pragma unroll
    for (int off = 32; off; off >>= 1) ss += __shfl_xor(ss, off);
    float d = 1.0f / sqrtf(ss + 1e-8f);

    unsigned short* slot = wsBF + (size_t)(1 + l*NB + b)*SLOT_HW;
#pragma unroll
    for (int u = 0; u < 4; ++u) {
        int k = lane + 64*u;
        int f = (o >> 4)*8 + (k >> 5);
        int hw = f*512 + ((k >> 3) & 3)*128 + (o & 15)*8 + (k & 7);
        slot[hw] = f2bf(wv[u]*d);
    }
}

// conv weights -> bf16 fragments, slot 0.
__global__ __launch_bounds__(256) void cwsplit_kernel(
    const float* __restrict__ cw, unsigned short* __restrict__ wsBF)
{
    int w = threadIdx.x >> 6, lane = threadIdx.x & 63;
    int m = blockIdx.x*4 + w;      // 0..255
#pragma unroll
    for (int u = 0; u < 4; ++u) {
        int k = lane + 64*u;
        int f = (m >> 4)*8 + (k >> 5);
        int hw = f*512 + ((k >> 3) & 3)*128 + (m & 15)*8 + (k & 7);
        wsBF[hw] = f2bf(cw[(size_t)m*CC + k]);
    }
}

// ---------------------------------------------------------------------------
// Fused: one block = (batch, full 64-px strip, all 256 channels). 256 blocks.
// A: bf16 fragments loaded global->VGPR (pre-barrier => latency hidden by the
//    barrier's own drain). Never touches LDS.
// B: fragment-packed LDS (reads = base + lane*16, conflict-free),
//    double-buffered => ONE barrier per K-quarter in the layer loop.
// State y1/y2 fp32 in regs (MFMA C/D layout); B split hi+lo => 2 MFMA/tile.
#define BFRAG(buf, nt, kcl, hl) \
    (lds + (buf)*16384 + ((((nt)*2 + (kcl))*2 + (hl)))*1024)

__global__ __launch_bounds__(512, 2) void fused_kernel(
    const float* __restrict__ x, const float* __restrict__ cb,
    const unsigned short* __restrict__ wsBF, float* __restrict__ out)
{
    // LDS 50176 B: Bbuf0 @0 (16 KB) | Bbuf1 @16384 (16 KB) | xS f32[64][68]
    // @32768 (17408). Conv epilogue overlays S2 f32[128][66] @0 (33792 B,
    // covers B0+B1+1KB of xS; all dead then).
    __shared__ __align__(16) unsigned char lds[50176];
    float* xS = (float*)(lds + 32768);
    float* S2 = (float*)lds;

    const int tid  = threadIdx.x;
    const int lane = tid & 63;
    const int wid  = tid >> 6;     // 0..7
    const int wm   = wid >> 1;     // 0..3  m base 64*wm
    const int wn   = wid & 1;      // 0..1  n base 32*wn
    const int l15  = lane & 15;
    const int q    = lane >> 4;    // 0..3

    // XCD swizzle: blockIdx%8 -> batch pair-slot; weights L2-resident per XCD
    const int bswz  = blockIdx.x & 7;
    const int b     = bswz >> 1;                           // 0..3
    const int strip = ((blockIdx.x >> 3) << 1) | (bswz & 1); // 0..63
    const int n0    = strip * 64;

    float y1[4][2][4], y2[4][2][4];
    f32x4 acc[4][2];

    // ---------------- conv GEMM:  acc = cw @ x[b]  ----------------
#pragma unroll
    for (int t = 0; t < 4; ++t)
#pragma unroll
        for (int s = 0; s < 2; ++s) acc[t][s] = 0;

    for (int kq = 0; kq < 4; ++kq) {
        int buf = kq & 1;
        {   // coalesced fp32 stage of x window [64k x 64n]
            int r0 = tid >> 4, c4 = (tid & 15) * 4;
#pragma unroll
            for (int p = 0; p < 2; ++p) {
                int row = r0 + 32*p;
                float4 v = *(const float4*)&x[((size_t)(b*CC + kq*64 + row))*4096 + n0 + c4];
                *(float4*)&xS[row*68 + c4] = v;
            }
        }
        __syncthreads();
        {   // transpose (conflict-free read) -> split bf16 -> B fragments
            int n = tid & 63, k0 = (tid >> 6) * 8;
            float f[8];
#pragma unroll
            for (int i = 0; i < 8; ++i) f[i] = xS[(k0+i)*68 + n];
            u16x8 hv, lv;
#pragma unroll
            for (int i = 0; i < 8; ++i) {
                unsigned short h = f2bf(f[i]);
                hv[i] = h; lv[i] = f2bf(f[i] - bf2f(h));
            }
            int nt = n >> 4, n15 = n & 15, kcl = k0 >> 5, qq = (k0 >> 3) & 3;
            *(u16x8*)(BFRAG(buf,nt,kcl,0) + (16*qq + n15)*16) = hv;
            *(u16x8*)(BFRAG(buf,nt,kcl,1) + (16*qq + n15)*16) = lv;
        }
        // A fragment loads global->reg, issued pre-barrier (drain = prefetch)
        s16x8 afr[2][4];
#pragma unroll
        for (int kcl = 0; kcl < 2; ++kcl)
#pragma unroll
        for (int t = 0; t < 4; ++t)
            afr[kcl][t] = *(const s16x8*)(wsBF + (size_t)((4*wm+t)*8 + kq*2+kcl)*512 + lane*8);
        __syncthreads();
#pragma unroll
        for (int kcl = 0; kcl < 2; ++kcl)
#pragma unroll
        for (int s = 0; s < 2; ++s) {
            int nt = 2*wn + s;
            s16x8 bh = *(const s16x8*)(BFRAG(buf,nt,kcl,0) + lane*16);
            s16x8 bl = *(const s16x8*)(BFRAG(buf,nt,kcl,1) + lane*16);
#pragma unroll
            for (int t = 0; t < 4; ++t) {
                acc[t][s] = __builtin_amdgcn_mfma_f32_16x16x32_bf16(afr[kcl][t], bh, acc[t][s], 0, 0, 0);
                acc[t][s] = __builtin_amdgcn_mfma_f32_16x16x32_bf16(afr[kcl][t], bl, acc[t][s], 0, 0, 0);
            }
        }
    }

    // conv epilogue: bias + channel-duplication remap via fp32 LDS scratch.
    // x1[c] = conv[c>>1]+cb, x2[c] = conv[128+(c>>1)]+cb
#pragma unroll
    for (int pass = 0; pass < 2; ++pass) {
        __syncthreads();
        if ((wm >> 1) == pass) {
#pragma unroll
            for (int t = 0; t < 4; ++t)
#pragma unroll
            for (int s = 0; s < 2; ++s)
#pragma unroll
            for (int r = 0; r < 4; ++r) {
                int m  = 64*wm + 16*t + 4*q + r;
                int nl = 32*wn + 16*s + l15;
                S2[(m - 128*pass)*66 + nl] = acc[t][s][r] + cb[m];
            }
        }
        __syncthreads();
#pragma unroll
        for (int t = 0; t < 4; ++t)
#pragma unroll
        for (int s = 0; s < 2; ++s)
#pragma unroll
        for (int r = 0; r < 4; ++r) {
            int c  = 64*wm + 16*t + 4*q + r;
            int nl = 32*wn + 16*s + l15;
            float v = S2[(c >> 1)*66 + nl];
            if (pass == 0) { y1[t][s][r] = v; }
            else           { y2[t][s][r] = v; y1[t][s][r] += v; }
        }
    }
    __syncthreads();   // S2 reads done before layer-0 staging reuses B region
    // y1 = x1+x2, y2 = x2

    // ---------------- 6 layers: 1 barrier per K-quarter ----------------
    for (int l = 0; l < NL; ++l) {
        const unsigned short* slot = wsBF + (size_t)(1 + l*NB + b)*SLOT_HW;
#pragma unroll
        for (int t = 0; t < 4; ++t)
#pragma unroll
            for (int s = 0; s < 2; ++s) acc[t][s] = 0;

        for (int kq = 0; kq < 4; ++kq) {
            int buf = kq & 1;
            // owner waves (wm==kq) stage y1 k-slice into B fragments
            if (wm == kq) {
#pragma unroll
                for (int t = 0; t < 4; ++t)
#pragma unroll
                for (int s = 0; s < 2; ++s) {
                    int nt = 2*wn + s, kcl = t >> 1;
                    int qq = 2*(t & 1) + (q >> 1), jb = 4*(q & 1);
                    u16x4 hv, lv;
#pragma unroll
                    for (int r = 0; r < 4; ++r) {
                        unsigned short h = f2bf(y1[t][s][r]);
                        hv[r] = h; lv[r] = f2bf(y1[t][s][r] - bf2f(h));
                    }
                    *(u16x4*)(BFRAG(buf,nt,kcl,0) + (16*qq + l15)*16 + jb*2) = hv;
                    *(u16x4*)(BFRAG(buf,nt,kcl,1) + (16*qq + l15)*16 + jb*2) = lv;
                }
            }
            // A fragment loads, pre-barrier
            s16x8 afr[2][4];
#pragma unroll
            for (int kcl = 0; kcl < 2; ++kcl)
#pragma unroll
            for (int t = 0; t < 4; ++t)
                afr[kcl][t] = *(const s16x8*)(slot + (size_t)((4*wm+t)*8 + kq*2+kcl)*512 + lane*8);
            __syncthreads();
#pragma unroll
            for (int kcl = 0; kcl < 2; ++kcl)
#pragma unroll
            for (int s = 0; s < 2; ++s) {
                int nt = 2*wn + s;
                s16x8 bh = *(const s16x8*)(BFRAG(buf,nt,kcl,0) + lane*16);
                s16x8 bl = *(const s16x8*)(BFRAG(buf,nt,kcl,1) + lane*16);
#pragma unroll
                for (int t = 0; t < 4; ++t) {
                    acc[t][s] = __builtin_amdgcn_mfma_f32_16x16x32_bf16(afr[kcl][t], bh, acc[t][s], 0, 0, 0);
                    acc[t][s] = __builtin_amdgcn_mfma_f32_16x16x32_bf16(afr[kcl][t], bl, acc[t][s], 0, 0, 0);
                }
            }
        }
        // y2 += gelu(h); y1 += y2 (next layer), skip on last
#pragma unroll
        for (int t = 0; t < 4; ++t)
#pragma unroll
        for (int s = 0; s < 2; ++s)
#pragma unroll
        for (int r = 0; r < 4; ++r) {
            y2[t][s][r] += gelu_fast(acc[t][s][r]);
            if (l < NL - 1) y1[t][s][r] += y2[t][s][r];
        }
    }

    // ---------------- out = 0.5*(y1+y2), 2x2 upsample ----------------
#pragma unroll
    for (int t = 0; t < 4; ++t)
#pragma unroll
    for (int s = 0; s < 2; ++s)
#pragma unroll
    for (int r = 0; r < 4; ++r) {
        int ch = 64*wm + 16*t + 4*q + r;
        int w  = 32*wn + 16*s + l15;          // 0..63 source col
        float v = 0.5f*(y1[t][s][r] + y2[t][s][r]);
        float2 vv = make_float2(v, v);
        size_t base = (((size_t)(b*CC + ch)*128 + 2*strip))*128 + 2*w;
        *(float2*)&out[base]       = vv;
        *(float2*)&out[base + 128] = vv;
    }
}

extern "C" void kernel_launch(void* const* d_in, const int* in_sizes, int n_in,
                              void* d_out, int out_size, void* d_ws, size_t ws_size,
                              hipStream_t stream) {
    const float* x  = (const float*)d_in[0];
    const float* y  = (const float*)d_in[1];
    const float* cw = (const float*)d_in[2];
    const float* cb = (const float*)d_in[3];
    const float* aw = (const float*)d_in[4];
    const float* ab = (const float*)d_in[5];
    const float* mw = (const float*)d_in[6];
    float* out = (float*)d_out;

    unsigned short* wsBF = (unsigned short*)d_ws;   // 25 slots * 128 KB = 3.2 MB

    wmod_kernel<<<NL*NB*CC/4, 256, 0, stream>>>(y, aw, ab, mw, wsBF);
    cwsplit_kernel<<<64, 256, 0, stream>>>(cw, wsBF);
    fused_kernel<<<256, 512, 0, stream>>>(x, cb, wsBF, out);
}

// Round 8
// 140.516 us; speedup vs baseline: 2.8962x; 1.0044x over previous
//
#include <hip/hip_runtime.h>
#include <math.h>

// (N, Cin, Cout, S, H, W) = (4, 256, 256, 512, 64, 64)
#define NB 4
#define CC 256
#define SS 512
#define NL 6
#define SLOT_HW 65536   // 128 KB per weight slot, MFMA-A-fragment-packed

typedef __attribute__((ext_vector_type(8))) short s16x8;
typedef __attribute__((ext_vector_type(4))) float f32x4;
typedef __attribute__((ext_vector_type(2))) float f32x2;
typedef __attribute__((ext_vector_type(4))) unsigned short u16x4;
typedef __attribute__((ext_vector_type(8))) unsigned short u16x8;

__device__ __forceinline__ unsigned short f2bf(float f) {
    unsigned u = __builtin_bit_cast(unsigned, f);
    u += 0x7FFFu + ((u >> 16) & 1u);
    return (unsigned short)(u >> 16);
}
__device__ __forceinline__ float bf2f(unsigned short h) {
    unsigned u = ((unsigned)h) << 16;
    return __builtin_bit_cast(float, u);
}
// gelu_exact(x) ~= x*sigmoid(1.5957691216*(x+0.044715x^3)), |err|<3e-3
__device__ __forceinline__ float gelu_fast(float x) {
    float u = x * (1.0f + 0.044715f * x * x);
    float e = __expf(-1.5957691216f * u);
    return x / (1.0f + e);
}

// Fragment-packed weight layout, per 256x256 GEMM slot (128 KB):
// fragment f = (m>>4)*8 + (k>>5); inside: halfword offset
//   ((k>>3)&3)*128 + (m&15)*8 + (k&7)
// so a wave's A-fragment read is slot + f*512 + lane*8 (16 B/lane contiguous).

// ---------------------------------------------------------------------------
__global__ __launch_bounds__(256) void wmod_kernel(
    const float* __restrict__ y, const float* __restrict__ aw,
    const float* __restrict__ ab, const float* __restrict__ mw,
    unsigned short* __restrict__ wsBF)
{
    int w = threadIdx.x >> 6, lane = threadIdx.x & 63;
    int r = blockIdx.x*4 + w;      // 0 .. 6143
    int l = r >> 10;
    int b = (r >> 8) & 3;
    int o = r & 255;

    const float* awr = aw + (size_t)(l*CC + o)*SS;
    const float* yb  = y + (size_t)b*SS;
    float s = 0.f;
#pragma unroll
    for (int j = 0; j < 8; ++j) { int idx = lane + 64*j; s += awr[idx]*yb[idx]; }
#pragma unroll
    for (int off = 32; off; off >>= 1) s += __shfl_xor(s, off);
    float t = s + ab[l*CC + o] + 1.0f;

    const float* mwr = mw + (size_t)(l*CC + o)*CC;
    float wv[4]; float ss = 0.f;
#pragma unroll
    for (int u = 0; u < 4; ++u) { int j = lane + 64*u; wv[u] = mwr[j]*t; ss += wv[u]*wv[u]; }
#pragma unroll
    for (int off = 32; off; off >>= 1) ss += __shfl_xor(ss, off);
    float d = 1.0f / sqrtf(ss + 1e-8f);

    unsigned short* slot = wsBF + (size_t)(1 + l*NB + b)*SLOT_HW;
#pragma unroll
    for (int u = 0; u < 4; ++u) {
        int k = lane + 64*u;
        int f = (o >> 4)*8 + (k >> 5);
        int hw = f*512 + ((k >> 3) & 3)*128 + (o & 15)*8 + (k & 7);
        slot[hw] = f2bf(wv[u]*d);
    }
}

__global__ __launch_bounds__(256) void cwsplit_kernel(
    const float* __restrict__ cw, unsigned short* __restrict__ wsBF)
{
    int w = threadIdx.x >> 6, lane = threadIdx.x & 63;
    int m = blockIdx.x*4 + w;      // 0..255
#pragma unroll
    for (int u = 0; u < 4; ++u) {
        int k = lane + 64*u;
        int f = (m >> 4)*8 + (k >> 5);
        int hw = f*512 + ((k >> 3) & 3)*128 + (m & 15)*8 + (k & 7);
        wsBF[hw] = f2bf(cw[(size_t)m*CC + k]);
    }
}

// ---------------------------------------------------------------------------
// Fused: one block = (batch, full 64-px strip, all 256 channels). 256 blocks.
// Layers: stage FULL B (64 KB, all K, hi+lo) once -> ONE long MFMA phase with
// A L2->VGPR prefetched 1 step ahead; 2 barriers/layer total.
// B-fragment LDS layout: frag(nt,kq,kcl,hl) of 1 KB, reads = base + lane*16.
#define BFRAG(nt, kq, kcl, hl) \
    (lds + (((((nt)*4 + (kq))*2 + (kcl))*2 + (hl)))*1024)

__global__ __launch_bounds__(512, 2) void fused_kernel(
    const float* __restrict__ x, const float* __restrict__ cb,
    const unsigned short* __restrict__ wsBF, float* __restrict__ out)
{
    // LDS 82944 B: B frags @0 (64 KB) | xS f32[64][68] @65536 (17408).
    // Conv epilogue overlays S2 f32[128][66] @0 (33792 B; conv MFMA done by
    // then, layer-0 staging only after the final epilogue sync).
    __shared__ __align__(16) unsigned char lds[82944];
    float* xS = (float*)(lds + 65536);
    float* S2 = (float*)lds;

    const int tid  = threadIdx.x;
    const int lane = tid & 63;
    const int wid  = tid >> 6;     // 0..7
    const int wm   = wid >> 1;     // 0..3  m base 64*wm; also owns k-quarter wm
    const int wn   = wid & 1;      // 0..1  n base 32*wn
    const int l15  = lane & 15;
    const int q    = lane >> 4;    // 0..3

    // XCD swizzle: blockIdx%8 -> batch pair-slot; weights L2-resident per XCD
    const int bswz  = blockIdx.x & 7;
    const int b     = bswz >> 1;                             // 0..3
    const int strip = ((blockIdx.x >> 3) << 1) | (bswz & 1); // 0..63
    const int n0    = strip * 64;

    float y1[4][2][4], y2[4][2][4];
    f32x4 acc[4][2];

    // ---------------- conv GEMM:  acc = cw @ x[b]  ----------------
#pragma unroll
    for (int t = 0; t < 4; ++t)
#pragma unroll
        for (int s = 0; s < 2; ++s) acc[t][s] = 0;

    for (int kq = 0; kq < 4; ++kq) {
        {   // coalesced fp32 stage of x window [64k x 64n]
            int r0 = tid >> 4, c4 = (tid & 15) * 4;
#pragma unroll
            for (int p = 0; p < 2; ++p) {
                int row = r0 + 32*p;
                float4 v = *(const float4*)&x[((size_t)(b*CC + kq*64 + row))*4096 + n0 + c4];
                *(float4*)&xS[row*68 + c4] = v;
            }
        }
        __syncthreads();
        {   // transpose (conflict-free read) -> split bf16 -> B frag slice kq
            int n = tid & 63, k0 = (tid >> 6) * 8;
            float f[8];
#pragma unroll
            for (int i = 0; i < 8; ++i) f[i] = xS[(k0+i)*68 + n];
            u16x8 hv, lv;
#pragma unroll
            for (int i = 0; i < 8; ++i) {
                unsigned short h = f2bf(f[i]);
                hv[i] = h; lv[i] = f2bf(f[i] - bf2f(h));
            }
            int nt = n >> 4, n15 = n & 15, kcl = k0 >> 5, qq = (k0 >> 3) & 3;
            *(u16x8*)(BFRAG(nt,kq,kcl,0) + (16*qq + n15)*16) = hv;
            *(u16x8*)(BFRAG(nt,kq,kcl,1) + (16*qq + n15)*16) = lv;
        }
        // A fragment loads global->reg, issued pre-barrier (drain = prefetch)
        s16x8 afr[2][4];
#pragma unroll
        for (int kcl = 0; kcl < 2; ++kcl)
#pragma unroll
        for (int t = 0; t < 4; ++t)
            afr[kcl][t] = *(const s16x8*)(wsBF + (size_t)((4*wm+t)*8 + kq*2+kcl)*512 + lane*8);
        __syncthreads();
#pragma unroll
        for (int kcl = 0; kcl < 2; ++kcl)
#pragma unroll
        for (int s = 0; s < 2; ++s) {
            int nt = 2*wn + s;
            s16x8 bh = *(const s16x8*)(BFRAG(nt,kq,kcl,0) + lane*16);
            s16x8 bl = *(const s16x8*)(BFRAG(nt,kq,kcl,1) + lane*16);
#pragma unroll
            for (int t = 0; t < 4; ++t) {
                acc[t][s] = __builtin_amdgcn_mfma_f32_16x16x32_bf16(afr[kcl][t], bh, acc[t][s], 0, 0, 0);
                acc[t][s] = __builtin_amdgcn_mfma_f32_16x16x32_bf16(afr[kcl][t], bl, acc[t][s], 0, 0, 0);
            }
        }
    }

    // conv epilogue: bias + channel-duplication remap via fp32 LDS scratch.
    // x1[c] = conv[c>>1]+cb, x2[c] = conv[128+(c>>1)]+cb
#pragma unroll
    for (int pass = 0; pass < 2; ++pass) {
        __syncthreads();
        if ((wm >> 1) == pass) {
#pragma unroll
            for (int t = 0; t < 4; ++t)
#pragma unroll
            for (int s = 0; s < 2; ++s)
#pragma unroll
            for (int r = 0; r < 4; ++r) {
                int m  = 64*wm + 16*t + 4*q + r;
                int nl = 32*wn + 16*s + l15;
                S2[(m - 128*pass)*66 + nl] = acc[t][s][r] + cb[m];
            }
        }
        __syncthreads();
#pragma unroll
        for (int t = 0; t < 4; ++t)
#pragma unroll
        for (int s = 0; s < 2; ++s)
#pragma unroll
        for (int r = 0; r < 4; ++r) {
            int c  = 64*wm + 16*t + 4*q + r;
            int nl = 32*wn + 16*s + l15;
            float v = S2[(c >> 1)*66 + nl];
            if (pass == 0) { y1[t][s][r] = v; }
            else           { y2[t][s][r] = v; y1[t][s][r] += v; }
        }
    }
    __syncthreads();   // S2 reads done before layer-0 staging reuses B region
    // y1 = x1+x2, y2 = x2

    // ---------------- 6 layers: 2 barriers per layer ----------------
    for (int l = 0; l < NL; ++l) {
        const unsigned short* slot = wsBF + (size_t)(1 + l*NB + b)*SLOT_HW;
#pragma unroll
        for (int t = 0; t < 4; ++t)
#pragma unroll
            for (int s = 0; s < 2; ++s) acc[t][s] = 0;

        // stage FULL B from y1 regs: wave (wm,wn) owns k-quarter wm, n-half wn
#pragma unroll
        for (int t = 0; t < 4; ++t)
#pragma unroll
        for (int s = 0; s < 2; ++s) {
            int nt = 2*wn + s, kcl = t >> 1;
            int qq = 2*(t & 1) + (q >> 1), jb = 4*(q & 1);
            u16x4 hv, lv;
#pragma unroll
            for (int r = 0; r < 4; ++r) {
                unsigned short h = f2bf(y1[t][s][r]);
                hv[r] = h; lv[r] = f2bf(y1[t][s][r] - bf2f(h));
            }
            *(u16x4*)(BFRAG(nt,wm,kcl,0) + (16*qq + l15)*16 + jb*2) = hv;
            *(u16x4*)(BFRAG(nt,wm,kcl,1) + (16*qq + l15)*16 + jb*2) = lv;
        }
        // prologue A prefetch for step 0 (issued before the barrier)
        s16x8 aN[4], aC[4];
#pragma unroll
        for (int t = 0; t < 4; ++t)
            aN[t] = *(const s16x8*)(slot + (size_t)((4*wm+t)*8 + 0)*512 + lane*8);
        __syncthreads();
        // ONE long MFMA phase: 8 steps, A prefetched 1 step ahead
#pragma unroll
        for (int step = 0; step < 8; ++step) {
#pragma unroll
            for (int t = 0; t < 4; ++t) aC[t] = aN[t];
            if (step < 7) {
#pragma unroll
                for (int t = 0; t < 4; ++t)
                    aN[t] = *(const s16x8*)(slot + (size_t)((4*wm+t)*8 + step+1)*512 + lane*8);
            }
            int kq = step >> 1, kcl = step & 1;
#pragma unroll
            for (int s = 0; s < 2; ++s) {
                int nt = 2*wn + s;
                s16x8 bh = *(const s16x8*)(BFRAG(nt,kq,kcl,0) + lane*16);
                s16x8 bl = *(const s16x8*)(BFRAG(nt,kq,kcl,1) + lane*16);
#pragma unroll
                for (int t = 0; t < 4; ++t) {
                    acc[t][s] = __builtin_amdgcn_mfma_f32_16x16x32_bf16(aC[t], bh, acc[t][s], 0, 0, 0);
                    acc[t][s] = __builtin_amdgcn_mfma_f32_16x16x32_bf16(aC[t], bl, acc[t][s], 0, 0, 0);
                }
            }
        }
        // y2 += gelu(h); y1 += y2 (next layer), skip on last
#pragma unroll
        for (int t = 0; t < 4; ++t)
#pragma unroll
        for (int s = 0; s < 2; ++s)
#pragma unroll
        for (int r = 0; r < 4; ++r) {
            y2[t][s][r] += gelu_fast(acc[t][s][r]);
            if (l < NL - 1) y1[t][s][r] += y2[t][s][r];
        }
        __syncthreads();   // all B reads done before next layer's staging
    }

    // ---------------- out = 0.5*(y1+y2), 2x2 upsample (nontemporal) --------
#pragma unroll
    for (int t = 0; t < 4; ++t)
#pragma unroll
    for (int s = 0; s < 2; ++s)
#pragma unroll
    for (int r = 0; r < 4; ++r) {
        int ch = 64*wm + 16*t + 4*q + r;
        int w  = 32*wn + 16*s + l15;          // 0..63 source col
        float v = 0.5f*(y1[t][s][r] + y2[t][s][r]);
        f32x2 vv = {v, v};
        size_t base = (((size_t)(b*CC + ch)*128 + 2*strip))*128 + 2*w;
        __builtin_nontemporal_store(vv, (f32x2*)&out[base]);
        __builtin_nontemporal_store(vv, (f32x2*)&out[base + 128]);
    }
}

extern "C" void kernel_launch(void* const* d_in, const int* in_sizes, int n_in,
                              void* d_out, int out_size, void* d_ws, size_t ws_size,
                              hipStream_t stream) {
    const float* x  = (const float*)d_in[0];
    const float* y  = (const float*)d_in[1];
    const float* cw = (const float*)d_in[2];
    const float* cb = (const float*)d_in[3];
    const float* aw = (const float*)d_in[4];
    const float* ab = (const float*)d_in[5];
    const float* mw = (const float*)d_in[6];
    float* out = (float*)d_out;

    unsigned short* wsBF = (unsigned short*)d_ws;   // 25 slots * 128 KB = 3.2 MB

    wmod_kernel<<<NL*NB*CC/4, 256, 0, stream>>>(y, aw, ab, mw, wsBF);
    cwsplit_kernel<<<64, 256, 0, stream>>>(cw, wsBF);
    fused_kernel<<<256, 512, 0, stream>>>(x, cb, wsBF, out);
}